// Round 3
// baseline (81.805 us; speedup 1.0000x reference)
//
#include <hip/hip_runtime.h>

typedef __attribute__((ext_vector_type(8))) __bf16 bf16x8;
typedef __attribute__((ext_vector_type(4))) float f32x4;

constexpr int Bn = 8192, Nn = 256, M1n = 128, M2n = 64, Mn = 192, ITERS = 30;
constexpr float TAUc = 0.05f, SIGc = 0.05f;

__device__ __forceinline__ ushort f2bf(float f) {
  unsigned u = __builtin_bit_cast(unsigned, f);
  u = (u + 0x7FFFu + ((u >> 16) & 1u)) >> 16;
  return (ushort)u;
}

// packed f32->bf16 (RNE), 2 values per instruction
__device__ __forceinline__ unsigned cvtpk(float lo, float hi) {
  unsigned r;
  asm("v_cvt_pk_bf16_f32 %0, %1, %2" : "=v"(r) : "v"(lo), "v"(hi));
  return r;
}

// Build bf16 copies of A = [A1;A2] in both orientations:
// Arm[m][n] (192x256 row-major), AT[n][m] (256x192 row-major).
__global__ void prep_kernel(const float* __restrict__ A1, const float* __restrict__ A2,
                            ushort* __restrict__ Arm, ushort* __restrict__ AT) {
  int i = blockIdx.x * 256 + threadIdx.x;
  if (i >= Mn * Nn) return;
  int m = i / Nn, n = i % Nn;
  float v = (m < M1n) ? A1[m * Nn + n] : A2[(m - M1n) * Nn + n];
  ushort b = f2bf(v);
  Arm[m * Nn + n] = b;
  AT[n * Mn + m] = b;
}

// 4 waves per block, one 16-row band per block.
// Wave w owns: GEMM-1 m-tiles {3w,3w+1,3w+2}; GEMM-3 n-tiles {4w..4w+3}.
// All A fragments register-resident (192 VGPR); z (pre-scaled by sigma) in LDS.
__global__ __launch_bounds__(256, 2) void pdhg_kernel(
    const float* __restrict__ x0, const float* __restrict__ y10,
    const float* __restrict__ y20, const float* __restrict__ z,
    const float* __restrict__ c, const ushort* __restrict__ Arm,
    const ushort* __restrict__ AT, float* __restrict__ out) {
  __shared__ __align__(16) ushort xb_lds[16][264];  // xbar band (bf16), padded
  __shared__ __align__(16) ushort y_lds[16][200];   // y band (bf16), padded
  __shared__ __align__(16) float z_lds[16][200];    // sigma*z band (f32), padded

  const int lane = threadIdx.x & 63;
  const int w = threadIdx.x >> 6;     // wave 0..3
  const int fr = lane & 15;           // fragment row (A-op) / col (B-op, C/D)
  const int kg = lane >> 4;           // k-group 0..3
  const int row0 = blockIdx.x * 16;   // this block's 16-row band

  // ---- stage sigma*z into LDS (read once per iter thereafter)
  for (int idx = threadIdx.x; idx < 16 * Mn; idx += 256) {
    int r = idx / Mn, m = idx - r * Mn;
    z_lds[r][m] = SIGc * z[(row0 + r) * Mn + m];
  }

  float x[4][4], cv[4], ys[3][4];

  // ---- init x state + initial xbar = x0 into LDS
#pragma unroll
  for (int t = 0; t < 4; ++t) {
    int n = (4 * w + t) * 16 + fr;
    cv[t] = c[n];
#pragma unroll
    for (int g = 0; g < 4; ++g) {
      float v = x0[(row0 + kg * 4 + g) * Nn + n];
      x[t][g] = v;
      xb_lds[kg * 4 + g][n] = f2bf(v);
    }
  }
  // ---- init y state
#pragma unroll
  for (int i = 0; i < 3; ++i) {
    int mt = 3 * w + i;
    int m = mt * 16 + fr;
#pragma unroll
    for (int g = 0; g < 4; ++g) {
      int r = row0 + kg * 4 + g;
      ys[i][g] = (m < M1n) ? y10[r * M1n + m] : y20[r * M2n + (m - M1n)];
    }
  }

  // ---- preload loop-invariant A fragments into registers (48 frags = 192 VGPR)
  bf16x8 armF[3][8], atF[4][6];
#pragma unroll
  for (int i = 0; i < 3; ++i) {
    int m = (3 * w + i) * 16 + fr;
#pragma unroll
    for (int kf = 0; kf < 8; ++kf)
      armF[i][kf] = *reinterpret_cast<const bf16x8*>(&Arm[m * Nn + kf * 32 + kg * 8]);
  }
#pragma unroll
  for (int t = 0; t < 4; ++t) {
    int n = (4 * w + t) * 16 + fr;
#pragma unroll
    for (int kf = 0; kf < 6; ++kf)
      atF[t][kf] = *reinterpret_cast<const bf16x8*>(&AT[n * Mn + kf * 32 + kg * 8]);
  }

  __syncthreads();

  for (int it = 0; it < ITERS; ++it) {
    // ---- GEMM-1: S = xbar @ A^T  (3 m-tiles; fx streamed from LDS)
    f32x4 a0 = {0.f, 0.f, 0.f, 0.f}, a1 = a0, a2 = a0;
#pragma unroll
    for (int kf = 0; kf < 8; ++kf) {
      bf16x8 fx = *reinterpret_cast<const bf16x8*>(&xb_lds[fr][kf * 32 + kg * 8]);
      a0 = __builtin_amdgcn_mfma_f32_16x16x32_bf16(fx, armF[0][kf], a0, 0, 0, 0);
      a1 = __builtin_amdgcn_mfma_f32_16x16x32_bf16(fx, armF[1][kf], a1, 0, 0, 0);
      a2 = __builtin_amdgcn_mfma_f32_16x16x32_bf16(fx, armF[2][kf], a2, 0, 0, 0);
    }

    // ---- y update (f32 state), write bf16 Y band to LDS
#pragma unroll
    for (int i = 0; i < 3; ++i) {
      int mt = 3 * w + i;
      int m = mt * 16 + fr;
      const f32x4 ai = (i == 0) ? a0 : (i == 1) ? a1 : a2;
#pragma unroll
      for (int g = 0; g < 4; ++g) {
        float s = __builtin_fmaf(SIGc, ai[g], ys[i][g]) - z_lds[kg * 4 + g][m];
        if (mt < 8) s = fmaxf(s, 0.f);  // tiles 0..7 -> y1 relu
        ys[i][g] = s;
      }
      unsigned p01 = cvtpk(ys[i][0], ys[i][1]);
      unsigned p23 = cvtpk(ys[i][2], ys[i][3]);
      y_lds[kg * 4 + 0][m] = (ushort)p01;
      y_lds[kg * 4 + 1][m] = (ushort)(p01 >> 16);
      y_lds[kg * 4 + 2][m] = (ushort)p23;
      y_lds[kg * 4 + 3][m] = (ushort)(p23 >> 16);
    }
    __syncthreads();

    // ---- GEMM-3: G = y @ A  (4 n-tiles; fy streamed from LDS)
    f32x4 b0 = {0.f, 0.f, 0.f, 0.f}, b1 = b0, b2 = b0, b3 = b0;
#pragma unroll
    for (int kf = 0; kf < 6; ++kf) {
      bf16x8 fy = *reinterpret_cast<const bf16x8*>(&y_lds[fr][kf * 32 + kg * 8]);
      b0 = __builtin_amdgcn_mfma_f32_16x16x32_bf16(fy, atF[0][kf], b0, 0, 0, 0);
      b1 = __builtin_amdgcn_mfma_f32_16x16x32_bf16(fy, atF[1][kf], b1, 0, 0, 0);
      b2 = __builtin_amdgcn_mfma_f32_16x16x32_bf16(fy, atF[2][kf], b2, 0, 0, 0);
      b3 = __builtin_amdgcn_mfma_f32_16x16x32_bf16(fy, atF[3][kf], b3, 0, 0, 0);
    }

    // ---- x update (f32 state), write bf16 xbar to LDS
    const bool notlast = (it != ITERS - 1);
#pragma unroll
    for (int t = 0; t < 4; ++t) {
      int n = (4 * w + t) * 16 + fr;
      const f32x4 bt = (t == 0) ? b0 : (t == 1) ? b1 : (t == 2) ? b2 : b3;
      float xb[4];
#pragma unroll
      for (int g = 0; g < 4; ++g) {
        float grad = cv[t] + bt[g];
        float xn = fmaxf(__builtin_fmaf(-TAUc, grad, x[t][g]), 0.f);
        xb[g] = 2.f * xn - x[t][g];  // theta = 1
        x[t][g] = xn;
      }
      if (notlast) {
        unsigned p01 = cvtpk(xb[0], xb[1]);
        unsigned p23 = cvtpk(xb[2], xb[3]);
        xb_lds[kg * 4 + 0][n] = (ushort)p01;
        xb_lds[kg * 4 + 1][n] = (ushort)(p01 >> 16);
        xb_lds[kg * 4 + 2][n] = (ushort)p23;
        xb_lds[kg * 4 + 3][n] = (ushort)(p23 >> 16);
      }
    }
    if (notlast) __syncthreads();
  }

  // ---- store outputs: x (B x 256), y1 (B x 128), y2 (B x 64), all f32
  float* ox = out;
  float* oy1 = out + Bn * Nn;
  float* oy2 = oy1 + Bn * M1n;
#pragma unroll
  for (int t = 0; t < 4; ++t) {
    int n = (4 * w + t) * 16 + fr;
#pragma unroll
    for (int g = 0; g < 4; ++g)
      ox[(row0 + kg * 4 + g) * Nn + n] = x[t][g];
  }
#pragma unroll
  for (int i = 0; i < 3; ++i) {
    int m = (3 * w + i) * 16 + fr;
#pragma unroll
    for (int g = 0; g < 4; ++g) {
      int r = row0 + kg * 4 + g;
      if (m < M1n) oy1[r * M1n + m] = ys[i][g];
      else         oy2[r * M2n + (m - M1n)] = ys[i][g];
    }
  }
}

extern "C" void kernel_launch(void* const* d_in, const int* in_sizes, int n_in,
                              void* d_out, int out_size, void* d_ws, size_t ws_size,
                              hipStream_t stream) {
  const float* x0  = (const float*)d_in[0];
  const float* y10 = (const float*)d_in[1];
  const float* y20 = (const float*)d_in[2];
  const float* z   = (const float*)d_in[3];
  const float* c   = (const float*)d_in[4];
  const float* A1  = (const float*)d_in[5];
  const float* A2  = (const float*)d_in[6];

  ushort* Arm = (ushort*)d_ws;          // 192*256 bf16
  ushort* AT  = Arm + Mn * Nn;          // 256*192 bf16

  prep_kernel<<<(Mn * Nn + 255) / 256, 256, 0, stream>>>(A1, A2, Arm, AT);
  pdhg_kernel<<<Bn / 16, 256, 0, stream>>>(x0, y10, y20, z, c, Arm, AT, (float*)d_out);
}